// Round 4
// baseline (783.886 us; speedup 1.0000x reference)
//
#include <hip/hip_runtime.h>
#include <hip/hip_bf16.h>
#include <hip/hip_fp16.h>

#define DEVINL __device__ __forceinline__
typedef __hip_bfloat16 bf16;

typedef __attribute__((ext_vector_type(8))) __bf16 bf16x8;
typedef __attribute__((ext_vector_type(4))) float f32x4;

static constexpr int N_NODES  = 50000;
static constexpr int N_EDGES  = 800000;
static constexpr int N_GRAPHS = 128;
static constexpr float NEG_SLOPE = 0.2f;
static constexpr int SLICE_G = 4096;          // slice_agg group-stride

// Dual-path input load: isbf=1 -> storage is bf16, else fp32.
DEVINL float ldIn(const void* __restrict__ p, size_t i, int isbf) {
    if (isbf) return __bfloat162float(((const bf16*)p)[i]);
    return ((const float*)p)[i];
}

DEVINL unsigned short f2bf(float f) {
    bf16 b = __float2bfloat16(f);
    return *reinterpret_cast<unsigned short*>(&b);
}

DEVINL unsigned f2hbits(float f) {
    __half h = __float2half(f);
    return (unsigned)*reinterpret_cast<unsigned short*>(&h);
}

DEVINL float hbits2f(unsigned bits) {
    unsigned short us = (unsigned short)bits;
    __half h = *reinterpret_cast<__half*>(&us);
    return __half2float(h);
}

DEVINL float lrelu_exp(float sc) {
    sc = sc > 0.f ? sc : NEG_SLOPE * sc;
    return __expf(sc);
}

// fma two bf16 channels packed in one dword into two f32 accumulators
DEVINL void accw(float w, unsigned wv, float& a0, float& a1) {
    a0 = fmaf(w, __uint_as_float(wv << 16), a0);
    a1 = fmaf(w, __uint_as_float(wv & 0xffff0000u), a1);
}

// ---------- W[K,M] -> MFMA B-fragment order (device helper) ----------
template<int K, int M>
DEVINL void wfrag_build(const void* __restrict__ W, int isbf,
                        bf16* __restrict__ Wfrag, int idx)
{
    constexpr int KS = K / 32;
    constexpr int total = (M / 16) * KS * 64 * 8;
    if (idx >= total) return;
    int j    = idx & 7;
    int lane = (idx >> 3) & 63;
    int rem  = idx >> 9;
    int ks   = rem % KS;
    int ct   = rem / KS;
    int k = ks * 32 + (lane >> 4) * 8 + j;
    int n = ct * 16 + (lane & 15);
    Wfrag[idx] = __float2bfloat16(ldIn(W, (size_t)k * M + n, isbf));
}

// ---------- fused setup: dtype sniff + M matrices + weight frags, ONE launch ----
__global__ __launch_bounds__(256)
void prep_kernel(const unsigned short* __restrict__ xu,
                 const void* __restrict__ We1, const void* __restrict__ ae1,
                 const void* __restrict__ We2, const void* __restrict__ ae2,
                 const void* __restrict__ W1,  const void* __restrict__ W2,
                 int* __restrict__ flagp,
                 float* __restrict__ M1, float* __restrict__ M2,
                 bf16* __restrict__ wf1, bf16* __restrict__ wf2)
{
    __shared__ int sflag;
    const int bx = blockIdx.x;
    const int t  = threadIdx.x;
    if (t < 64) {                       // wave 0, fully active
        int bad = 0;
        for (int i = t; i < 1024; i += 64) {
            unsigned u = xu[2 * i];
            float v = __uint_as_float(u << 16);
            if (!(fabsf(v) <= 1e4f)) bad = 1;
        }
        unsigned long long m = __ballot(bad);
        if (t == 0) sflag = m ? 0 : 1;  // 1 = bf16 storage
    }
    __syncthreads();
    const int isbf = sflag;
    if (bx == 0 && t == 0) *flagp = isbf;

    if (bx == 0) {
        if (t < 64) {
            int d = t >> 2, h = t & 3;
            float s = 0.f;
            for (int c = 0; c < 64; ++c)
                s += ldIn(We1, d * 256 + h * 64 + c, isbf) * ldIn(ae1, h * 64 + c, isbf);
            M1[d * 4 + h] = s;
        }
        if (t < 32) {
            int d = t >> 1, h = t & 1;
            float s = 0.f;
            for (int c = 0; c < 64; ++c)
                s += ldIn(We2, d * 128 + h * 64 + c, isbf) * ldIn(ae2, h * 64 + c, isbf);
            M2[d * 2 + h] = s;
        }
    } else if (bx <= 128) {
        wfrag_build<128, 256>(W1, isbf, wf1, (bx - 1) * 256 + t);
    } else {
        wfrag_build<256, 128>(W2, isbf, wf2, (bx - 129) * 256 + t);
    }
}

// ---------- MFMA GEMM + fused node-score epilogue ----------
// SLICED=1: C written slice-major [M/32][N][32] (layer-1 table for slice_agg).
template<int K, int M, int AMODE, int H, int SLICED>
__global__ __launch_bounds__(256)
void gemm_mfma_kernel(const void* __restrict__ A, const bf16* __restrict__ Wfrag,
                      bf16* __restrict__ C, const int* __restrict__ flagp, int N,
                      const void* __restrict__ a_src, const void* __restrict__ a_dst,
                      float* __restrict__ sA, float* __restrict__ sD)
{
    constexpr int KS = K / 32, CT = M / 16;
    constexpr int LDA = K + 8;
    __shared__ __align__(16) unsigned short Asm[64 * LDA];
    const int isbf = *flagp;
    const int tid  = threadIdx.x;
    const int wave = tid >> 6, lane = tid & 63;
    const int n0 = blockIdx.x * 64;

    for (int i = tid; i < 64 * (K / 8); i += 256) {
        int r  = i / (K / 8);
        int kc = (i % (K / 8)) * 8;
        int n  = n0 + r;
        unsigned short v[8] = {0, 0, 0, 0, 0, 0, 0, 0};
        if (n < N) {
            size_t base = (size_t)n * K + kc;
            if (AMODE == 1 || isbf) {
                *reinterpret_cast<uint4*>(v) =
                    *reinterpret_cast<const uint4*>((const unsigned short*)A + base);
            } else {
                const float* Af = (const float*)A + base;
                float4 f0 = *reinterpret_cast<const float4*>(Af);
                float4 f1 = *reinterpret_cast<const float4*>(Af + 4);
                v[0] = f2bf(f0.x); v[1] = f2bf(f0.y); v[2] = f2bf(f0.z); v[3] = f2bf(f0.w);
                v[4] = f2bf(f1.x); v[5] = f2bf(f1.y); v[6] = f2bf(f1.z); v[7] = f2bf(f1.w);
            }
        }
        *reinterpret_cast<uint4*>(&Asm[r * LDA + kc]) = *reinterpret_cast<uint4*>(v);
    }
    __syncthreads();

    f32x4 acc[CT];
    #pragma unroll
    for (int ct = 0; ct < CT; ++ct) acc[ct] = (f32x4){0.f, 0.f, 0.f, 0.f};

    const int arow  = wave * 16 + (lane & 15);
    const int akoff = (lane >> 4) * 8;
    #pragma unroll
    for (int ks = 0; ks < KS; ++ks) {
        bf16x8 af = *reinterpret_cast<const bf16x8*>(&Asm[arow * LDA + ks * 32 + akoff]);
        #pragma unroll
        for (int ct = 0; ct < CT; ++ct) {
            bf16x8 bfr = *reinterpret_cast<const bf16x8*>(
                &Wfrag[(((size_t)ct * KS + ks) * 64 + lane) * 8]);
            acc[ct] = __builtin_amdgcn_mfma_f32_16x16x32_bf16(af, bfr, acc[ct], 0, 0, 0);
        }
    }

    const int crow0 = n0 + wave * 16 + (lane >> 4) * 4;
    const int ccol  = lane & 15;
    #pragma unroll
    for (int ct = 0; ct < CT; ++ct) {
        #pragma unroll
        for (int r = 0; r < 4; ++r) {
            int row = crow0 + r;
            if (row < N) {
                bf16 val = __float2bfloat16(acc[ct][r]);
                if (SLICED) {
                    int col = ct * 16 + ccol;
                    C[(size_t)(col >> 5) * ((size_t)N * 32) + (size_t)row * 32 + (col & 31)] = val;
                } else {
                    C[(size_t)row * M + ct * 16 + ccol] = val;
                }
            }
        }
    }

    // ---- fused attention logits ----
    float psA[4][H], psD[4][H];
    #pragma unroll
    for (int r = 0; r < 4; ++r)
        #pragma unroll
        for (int hh = 0; hh < H; ++hh) { psA[r][hh] = 0.f; psD[r][hh] = 0.f; }
    #pragma unroll
    for (int ct = 0; ct < CT; ++ct) {
        float as = ldIn(a_src, ct * 16 + ccol, isbf);
        float ad = ldIn(a_dst, ct * 16 + ccol, isbf);
        const int hh = ct >> 2;
        #pragma unroll
        for (int r = 0; r < 4; ++r) {
            psA[r][hh] += acc[ct][r] * as;
            psD[r][hh] += acc[ct][r] * ad;
        }
    }
    #pragma unroll
    for (int m = 1; m < 16; m <<= 1) {
        #pragma unroll
        for (int r = 0; r < 4; ++r)
            #pragma unroll
            for (int hh = 0; hh < H; ++hh) {
                psA[r][hh] += __shfl_xor(psA[r][hh], m);
                psD[r][hh] += __shfl_xor(psD[r][hh], m);
            }
    }
    if (ccol == 0) {
        #pragma unroll
        for (int r = 0; r < 4; ++r) {
            int row = crow0 + r;
            if (row < N) {
                #pragma unroll
                for (int hh = 0; hh < H; ++hh) {
                    sA[(size_t)row * H + hh] = psA[r][hh];
                    sD[(size_t)row * H + hh] = psD[r][hh];
                }
            }
        }
    }
}

// ---------- CSR build: count + per-edge stable rank (atomic return) ----------
__global__ void csr_count_kernel(const int* __restrict__ dst, int* __restrict__ cnt,
                                 int* __restrict__ rank)
{
    int e = blockIdx.x * blockDim.x + threadIdx.x;
    if (e >= N_EDGES) return;
    rank[e] = atomicAdd(&cnt[dst[e]], 1);
}

__global__ __launch_bounds__(256)
void scan_sum_kernel(const int* __restrict__ cnt, int* __restrict__ bsum)
{
    __shared__ int sm[256];
    int i = blockIdx.x * 256 + threadIdx.x;
    sm[threadIdx.x] = (i < N_NODES) ? cnt[i] : 0;
    __syncthreads();
    for (int off = 128; off; off >>= 1) {
        if (threadIdx.x < off) sm[threadIdx.x] += sm[threadIdx.x + off];
        __syncthreads();
    }
    if (threadIdx.x == 0) bsum[blockIdx.x] = sm[0];
}

__global__ __launch_bounds__(256)
void scan_off_kernel(int* __restrict__ bsum, int nb)
{
    __shared__ int sm[256];
    int tid = threadIdx.x;
    int v = (tid < nb) ? bsum[tid] : 0;
    sm[tid] = v;
    __syncthreads();
    for (int off = 1; off < 256; off <<= 1) {
        int t = (tid >= off) ? sm[tid - off] : 0;
        __syncthreads();
        sm[tid] += t;
        __syncthreads();
    }
    if (tid < nb) bsum[tid] = sm[tid] - v;
}

__global__ __launch_bounds__(256)
void scan_final_kernel(const int* __restrict__ cnt, const int* __restrict__ bsum,
                       int* __restrict__ row)
{
    __shared__ int sm[256];
    int i = blockIdx.x * 256 + threadIdx.x;
    int tid = threadIdx.x;
    int v = (i < N_NODES) ? cnt[i] : 0;
    sm[tid] = v;
    __syncthreads();
    for (int off = 1; off < 256; off <<= 1) {
        int t = (tid >= off) ? sm[tid - off] : 0;
        __syncthreads();
        sm[tid] += t;
        __syncthreads();
    }
    int excl = sm[tid] - v + bsum[blockIdx.x];
    if (i < N_NODES) row[i] = excl;
    if (i == N_NODES - 1) row[N_NODES] = excl + v;
}

// ---------- scatter + per-edge SCORE (computed once, not per-lane) ----------
// Writes per-head planes wrec[h][pos] = src(16b) | w_half(16b)  (src < 2^16),
// lean layer-2 records rec2[pos] = (src, 2x se2 half), and atomically
// accumulates denf[d][h] (half-ROUNDED w -> numerator/denominator consistent)
// and seSum[d][h] (for the mean-attr self loop).
__global__ __launch_bounds__(256)
void scatter_score_kernel(const int* __restrict__ srcI, const int* __restrict__ dstI,
                          const void* __restrict__ eattr, const int* __restrict__ flagp,
                          const float* __restrict__ M1, const float* __restrict__ M2,
                          const int* __restrict__ row, const int* __restrict__ rank,
                          const float* __restrict__ sA1, const float* __restrict__ sD1,
                          unsigned* __restrict__ wrec, uint2* __restrict__ rec2,
                          float* __restrict__ denf, float* __restrict__ seSum)
{
    const int isbf = *flagp;
    int e = blockIdx.x * blockDim.x + threadIdx.x;
    if (e >= N_EDGES) return;
    float attr[16];
    #pragma unroll
    for (int k = 0; k < 16; ++k) attr[k] = ldIn(eattr, (size_t)e * 16 + k, isbf);
    float o1a[4] = {0.f, 0.f, 0.f, 0.f};
    float o2a[2] = {0.f, 0.f};
    #pragma unroll
    for (int k = 0; k < 16; ++k) {
        #pragma unroll
        for (int h = 0; h < 4; ++h) o1a[h] += attr[k] * M1[k * 4 + h];
        #pragma unroll
        for (int h = 0; h < 2; ++h) o2a[h] += attr[k] * M2[k * 2 + h];
    }
    const int sidx = srcI[e];
    const int d    = dstI[e];
    const int pos  = row[d] + rank[e];
    float4 sav = *reinterpret_cast<const float4*>(&sA1[(size_t)sidx * 4]);
    float4 sdv = *reinterpret_cast<const float4*>(&sD1[(size_t)d * 4]);
    float sa[4] = {sav.x, sav.y, sav.z, sav.w};
    float sd[4] = {sdv.x, sdv.y, sdv.z, sdv.w};
    #pragma unroll
    for (int h = 0; h < 4; ++h) {
        unsigned whb = f2hbits(lrelu_exp(sa[h] + sd[h] + o1a[h]));
        float wr = hbits2f(whb);                     // rounded value -> consistent den
        atomicAdd(&denf[(size_t)d * 4 + h], wr);
        atomicAdd(&seSum[(size_t)d * 4 + h], o1a[h]);
        wrec[(size_t)h * N_EDGES + pos] = (unsigned)sidx | (whb << 16);
    }
    rec2[pos] = make_uint2((unsigned)sidx, f2hbits(o2a[0]) | (f2hbits(o2a[1]) << 16));
}

// ---------- self-loop weights: denf += wself; publish wself ----------
__global__ __launch_bounds__(256)
void self_kernel(const int* __restrict__ cnt,
                 const float* __restrict__ sA1, const float* __restrict__ sD1,
                 float* __restrict__ denf, const float* __restrict__ seSum,
                 float* __restrict__ wself)
{
    int i = blockIdx.x * 256 + threadIdx.x;
    if (i >= N_NODES) return;
    float rc = 1.f / fmaxf((float)cnt[i], 1.f);
    float4 dv = *reinterpret_cast<const float4*>(&denf[(size_t)i * 4]);
    float4 ss = *reinterpret_cast<const float4*>(&seSum[(size_t)i * 4]);
    float4 sa = *reinterpret_cast<const float4*>(&sA1[(size_t)i * 4]);
    float4 sd = *reinterpret_cast<const float4*>(&sD1[(size_t)i * 4]);
    float w0 = lrelu_exp(sa.x + sd.x + ss.x * rc);
    float w1 = lrelu_exp(sa.y + sd.y + ss.y * rc);
    float w2 = lrelu_exp(sa.z + sd.z + ss.z * rc);
    float w3 = lrelu_exp(sa.w + sd.w + ss.w * rc);
    dv.x += w0; dv.y += w1; dv.z += w2; dv.w += w3;
    *reinterpret_cast<float4*>(&denf[(size_t)i * 4])  = dv;
    *reinterpret_cast<float4*>(&wself[(size_t)i * 4]) = make_float4(w0, w1, w2, w3);
}

// ---------- layer-1 aggregate, XCD-sliced: slice = blockIdx.x & 7 ----------
// Table is slice-major [8][N][32ch] bf16 (64-B rows): each XCD's gather working
// set is 3.2 MB < 4 MB L2 -> per-XCD fetch ~= compulsory. Pure gather+FMA
// (scores precomputed in scatter_score). 4 lanes/edge x 16 edges per wave.
__global__ __launch_bounds__(256)
void slice_agg_kernel(const int* __restrict__ rowp, const unsigned* __restrict__ wrec,
                      const bf16* __restrict__ xs, const float* __restrict__ denf,
                      const float* __restrict__ wself, const void* __restrict__ bias,
                      const int* __restrict__ flagp, unsigned short* __restrict__ out)
{
    const int isbf  = *flagp;
    const int slice = blockIdx.x & 7;
    const int h     = slice >> 1;
    const int wave  = threadIdx.x >> 6;
    const int lane  = threadIdx.x & 63;
    const int eg    = lane >> 2;                    // edge slot 0..15
    const int co    = lane & 3;                     // 16-B chunk within 64-B row
    const char* xsb = (const char*)xs + (size_t)slice * ((size_t)N_NODES * 64);
    const unsigned* wp = wrec + (size_t)h * N_EDGES;

    for (int grp = blockIdx.x >> 3; grp < (N_NODES + 3) / 4; grp += SLICE_G) {
        const int d = __builtin_amdgcn_readfirstlane(grp * 4 + wave);
        if (d >= N_NODES) continue;
        const int b = rowp[d], eend = rowp[d + 1];

        float acc[8];
        #pragma unroll
        for (int i = 0; i < 8; ++i) acc[i] = 0.f;

        for (int j0 = b; j0 < eend; j0 += 16) {
            int j = j0 + eg;
            bool valid = j < eend;
            int jc = valid ? j : (eend - 1);
            unsigned wr = wp[jc];
            int s = (int)(wr & 0xffffu);
            float w = valid ? hbits2f(wr >> 16) : 0.f;
            uint4 xv = *reinterpret_cast<const uint4*>(xsb + (size_t)s * 64 + co * 16);
            const unsigned* wv = reinterpret_cast<const unsigned*>(&xv);
            #pragma unroll
            for (int p = 0; p < 4; ++p) accw(w, wv[p], acc[2 * p], acc[2 * p + 1]);
        }

        // butterfly across the 16 edge-groups (lane bits 2..5)
        #pragma unroll
        for (int i = 0; i < 8; ++i) {
            acc[i] += __shfl_xor(acc[i], 4);
            acc[i] += __shfl_xor(acc[i], 8);
            acc[i] += __shfl_xor(acc[i], 16);
            acc[i] += __shfl_xor(acc[i], 32);
        }

        // self loop + normalize
        const float wS   = wself[(size_t)d * 4 + h];
        const float rden = 1.f / (denf[(size_t)d * 4 + h] + 1e-16f);
        uint4 xvS = *reinterpret_cast<const uint4*>(xsb + (size_t)d * 64 + co * 16);
        const unsigned* wv = reinterpret_cast<const unsigned*>(&xvS);
        #pragma unroll
        for (int p = 0; p < 4; ++p) accw(wS, wv[p], acc[2 * p], acc[2 * p + 1]);

        if (eg == 0) {
            unsigned o[4];
            #pragma unroll
            for (int p = 0; p < 4; ++p) {
                int ch = slice * 32 + co * 8 + 2 * p;
                float v0 = acc[2 * p] * rden + ldIn(bias, ch, isbf);
                float v1 = acc[2 * p + 1] * rden + ldIn(bias, ch + 1, isbf);
                v0 = v0 > 0.f ? v0 : 0.f;
                v1 = v1 > 0.f ? v1 : 0.f;
                o[p] = (unsigned)f2bf(v0) | ((unsigned)f2bf(v1) << 16);
            }
            *reinterpret_cast<uint4*>(&out[(size_t)d * 256 + slice * 32 + co * 8]) =
                *reinterpret_cast<uint4*>(o);
        }
    }
}

// ---------- layer-2 aggregate: round-1 quad structure, lean 8-B records ----------
__global__ __launch_bounds__(256)
void agg2_kernel(const int* __restrict__ row, const uint2* __restrict__ rec2,
                 const bf16* __restrict__ xs,
                 const float* __restrict__ sA, const float* __restrict__ sD,
                 const void* __restrict__ bias,
                 const int* __restrict__ flagp, float* __restrict__ out)
{
    const int isbf = *flagp;
    int dv = (blockIdx.x * 256 + threadIdx.x) >> 6;
    const int d = __builtin_amdgcn_readfirstlane(dv);
    const int lane = threadIdx.x & 63;
    if (d >= N_NODES) return;
    const int q  = lane >> 4;                       // which edge of the quad
    const int sl = lane & 15;                       // slot within the row
    const int h  = sl >> 3;                         // head (2 x 64ch)
    const char* xsb = (const char*)xs;
    const unsigned lb = (unsigned)(sl * 16);        // lane byte offset in 256-B row
    const float sDv = sD[(size_t)d * 2 + h];
    const float sAd = sA[(size_t)d * 2 + h];

    float acc[8];
    #pragma unroll
    for (int i = 0; i < 8; ++i) acc[i] = 0.f;
    float den = 0.f, seSum = 0.f;

    const int b = row[d], eend = row[d + 1];
    const int cnt = eend - b;
    const int nb8 = cnt & ~7;

    for (int j0 = b; j0 < b + nb8; j0 += 8) {
        uint2 rv0 = rec2[j0 + q];
        uint2 rv1 = rec2[j0 + 4 + q];
        int s0 = (int)rv0.x, s1 = (int)rv1.x;
        const uint4* p0 = (const uint4*)(xsb + (size_t)((unsigned)s0 * 256 + lb));
        const uint4* p1 = (const uint4*)(xsb + (size_t)((unsigned)s1 * 256 + lb));
        uint4 xv0 = *p0, xv1 = *p1;
        float sa0 = sA[(size_t)s0 * 2 + h];
        float sa1 = sA[(size_t)s1 * 2 + h];
        float se0 = hbits2f(h ? (rv0.y >> 16) : (rv0.y & 0xffffu));
        float se1 = hbits2f(h ? (rv1.y >> 16) : (rv1.y & 0xffffu));
        float w0 = lrelu_exp(sa0 + sDv + se0);
        float w1 = lrelu_exp(sa1 + sDv + se1);
        seSum += se0 + se1;
        den += w0 + w1;
        const unsigned* wv0 = reinterpret_cast<const unsigned*>(&xv0);
        const unsigned* wv1 = reinterpret_cast<const unsigned*>(&xv1);
        #pragma unroll
        for (int p = 0; p < 4; ++p) {
            accw(w0, wv0[p], acc[2 * p], acc[2 * p + 1]);
            accw(w1, wv1[p], acc[2 * p], acc[2 * p + 1]);
        }
    }
    for (int j0 = b + nb8; j0 < eend; j0 += 4) {     // masked tail quads
        int jj = j0 + q;
        bool valid = jj < eend;
        int jc = valid ? jj : (eend - 1);
        uint2 rv = rec2[jc];
        int s = (int)rv.x;
        float se = hbits2f(h ? (rv.y >> 16) : (rv.y & 0xffffu));
        float sa = sA[(size_t)s * 2 + h];
        uint4 xv = *(const uint4*)(xsb + (size_t)((unsigned)s * 256 + lb));
        float w = valid ? lrelu_exp(sa + sDv + se) : 0.f;
        seSum += valid ? se : 0.f;
        den += w;
        const unsigned* wv = reinterpret_cast<const unsigned*>(&xv);
        #pragma unroll
        for (int p = 0; p < 4; ++p) accw(w, wv[p], acc[2 * p], acc[2 * p + 1]);
    }

    // cross-quad butterfly reduce
    #pragma unroll
    for (int i = 0; i < 8; ++i) {
        acc[i] += __shfl_xor(acc[i], 16);
        acc[i] += __shfl_xor(acc[i], 32);
    }
    den   += __shfl_xor(den, 16);   den   += __shfl_xor(den, 32);
    seSum += __shfl_xor(seSum, 16); seSum += __shfl_xor(seSum, 32);

    // self loop
    {
        const float seM = seSum / fmaxf((float)cnt, 1.f);
        const float wS  = lrelu_exp(sAd + sDv + seM);
        uint4 xv = *(const uint4*)(xsb + (size_t)((unsigned)d * 256 + lb));
        den += wS;
        const unsigned* wv = reinterpret_cast<const unsigned*>(&xv);
        #pragma unroll
        for (int p = 0; p < 4; ++p) accw(wS, wv[p], acc[2 * p], acc[2 * p + 1]);
    }

    const float rden = 1.f / (den + 1e-16f);
    // lanes sl<8 hold head0 chans sl*8..+7; sl^8 holds head1 same offsets
    float v[8], pp[8];
    #pragma unroll
    for (int i = 0; i < 8; ++i) {
        v[i] = acc[i] * rden;
        pp[i] = __shfl_xor(v[i], 8);
    }
    if (q == 0 && sl < 8) {
        float o[8];
        #pragma unroll
        for (int i = 0; i < 8; ++i)
            o[i] = 0.5f * (v[i] + pp[i]) + ldIn(bias, sl * 8 + i, isbf);
        float4* op = reinterpret_cast<float4*>(&out[(size_t)d * 64 + sl * 8]);
        op[0] = reinterpret_cast<float4*>(o)[0];
        op[1] = reinterpret_cast<float4*>(o)[1];
    }
}

// ---------- fused pooling + readout ----------
__global__ __launch_bounds__(256)
void pool_readout_kernel(const float* __restrict__ h2, const int* __restrict__ batch,
                         const void* __restrict__ Wr, const void* __restrict__ br,
                         const int* __restrict__ flagp, void* __restrict__ out)
{
    const int isbf = *flagp;
    int gi = blockIdx.x;
    int lo = 0, hi = N_NODES;
    while (lo < hi) { int mid = (lo + hi) >> 1; if (batch[mid] < gi) lo = mid + 1; else hi = mid; }
    int start = lo;
    lo = start; hi = N_NODES;
    while (lo < hi) { int mid = (lo + hi) >> 1; if (batch[mid] < gi + 1) lo = mid + 1; else hi = mid; }
    int end = lo;
    int c = threadIdx.x & 63, chunk = threadIdx.x >> 6;
    float m = -INFINITY;
    for (int n = start + chunk; n < end; n += 4) m = fmaxf(m, h2[(size_t)n * 64 + c]);
    __shared__ float sm[256];
    sm[threadIdx.x] = m;
    __syncthreads();
    if (threadIdx.x < 64) {
        m = fmaxf(fmaxf(sm[threadIdx.x], sm[threadIdx.x + 64]),
                  fmaxf(sm[threadIdx.x + 128], sm[threadIdx.x + 192]));
        float p = m * ldIn(Wr, threadIdx.x, isbf);
        for (int off = 32; off; off >>= 1) p += __shfl_down(p, off);
        if (threadIdx.x == 0) {
            float r = p + ldIn(br, 0, isbf);
            if (isbf) ((bf16*)out)[gi] = __float2bfloat16(r);
            else      ((float*)out)[gi] = r;
        }
    }
}

extern "C" void kernel_launch(void* const* d_in, const int* in_sizes, int n_in,
                              void* d_out, int out_size, void* d_ws, size_t ws_size,
                              hipStream_t stream)
{
    const void* x     = d_in[0];
    const void* ea    = d_in[1];
    const int*  eidx  = (const int*)d_in[2];
    const int*  batch = (const int*)d_in[3];
    const void* W1  = d_in[4];
    const void* as1 = d_in[5];
    const void* ad1 = d_in[6];
    const void* We1 = d_in[7];
    const void* ae1 = d_in[8];
    const void* b1  = d_in[9];
    const void* W2  = d_in[10];
    const void* as2 = d_in[11];
    const void* ad2 = d_in[12];
    const void* We2 = d_in[13];
    const void* ae2 = d_in[14];
    const void* b2  = d_in[15];
    const void* Wr  = d_in[16];
    const void* br  = d_in[17];

    const int* srcI = eidx;
    const int* dstI = eidx + N_EDGES;

    // ---- workspace layout (float-index offsets), peak ~79 MB ----
    float* ws    = (float*)d_ws;
    bf16*  xs    = (bf16*)ws;                      // L1: sliced [8][N][32] 25.6MB; L2: [N][128]
    bf16*  h1    = (bf16*)(ws + 6400000);          // N*256 bf16 (25.6MB)
    float* h2    = ws + 6400000;                   // N*64 fp32 overlay (h1 dead after gemm2)
    uint2* rec2  = (uint2*)(ws + 12800000);        // E 8-B records (6.4MB)
    float* sA1   = ws + 14400000;                  // N*4
    float* sD1   = ws + 14600000;                  // N*4
    float* sA2   = ws + 14800000;                  // N*2
    float* sD2   = ws + 14900000;                  // N*2
    float* wself = ws + 15000000;                  // N*4
    // --- contiguous memset region: cnt + denf + seSum ---
    int*   cnt   = (int*)(ws + 15200000);          // N (pad 50016)
    float* denf  = ws + 15250016;                  // N*4
    float* seSum = ws + 15450016;                  // N*4
    int*   row   = (int*)(ws + 15650016);          // N+1 (pad 50016)
    int*   bsum  = (int*)(ws + 15700032);          // 256 (pad 352)
    int*   rank  = (int*)(ws + 15700384);          // E
    unsigned* wrec = (unsigned*)(ws + 16500384);   // 4 planes x E x 4B (12.8MB)
    float* misc  = ws + 19700400;
    int*   flag  = (int*)misc;                     // 1
    float* M1    = misc + 16;                      // 64
    float* M2    = misc + 80;                      // 32
    bf16*  wf1   = (bf16*)(misc + 128);            // 32768 bf16
    bf16*  wf2   = (bf16*)(misc + 128 + 16384);    // 32768 bf16

    // one memset: cnt (200KB) + denf (800KB) + seSum (800KB)
    hipMemsetAsync(cnt, 0, 450016 * sizeof(float), stream);

    prep_kernel<<<257, 256, 0, stream>>>((const unsigned short*)x,
                                         We1, ae1, We2, ae2, W1, W2, flag,
                                         M1, M2, wf1, wf2);

    // ----- CSR over dst (parallel scan) -----
    const int NB = (N_NODES + 255) / 256;          // 196
    csr_count_kernel<<<(N_EDGES + 255) / 256, 256, 0, stream>>>(dstI, cnt, rank);
    scan_sum_kernel<<<NB, 256, 0, stream>>>(cnt, bsum);
    scan_off_kernel<<<1, 256, 0, stream>>>(bsum, NB);
    scan_final_kernel<<<NB, 256, 0, stream>>>(cnt, bsum, row);

    const int GB = (N_NODES + 63) / 64;            // 782 row-blocks

    // ----- layer 1: GEMM (sliced C) -> per-edge scores -> self -> sliced agg -----
    gemm_mfma_kernel<128, 256, 0, 4, 1><<<GB, 256, 0, stream>>>(
        x, wf1, xs, flag, N_NODES, as1, ad1, sA1, sD1);
    scatter_score_kernel<<<(N_EDGES + 255) / 256, 256, 0, stream>>>(
        srcI, dstI, ea, flag, M1, M2, row, rank, sA1, sD1, wrec, rec2, denf, seSum);
    self_kernel<<<NB, 256, 0, stream>>>(cnt, sA1, sD1, denf, seSum, wself);
    slice_agg_kernel<<<8 * SLICE_G, 256, 0, stream>>>(
        row, wrec, xs, denf, wself, b1, flag, (unsigned short*)h1);

    // ----- layer 2 (H=2, mean) -----
    gemm_mfma_kernel<256, 128, 1, 2, 0><<<GB, 256, 0, stream>>>(
        h1, wf2, xs, flag, N_NODES, as2, ad2, sA2, sD2);
    agg2_kernel<<<(N_NODES + 3) / 4, 256, 0, stream>>>(
        row, rec2, xs, sA2, sD2, b2, flag, h2);

    // ----- fused pool + readout -----
    pool_readout_kernel<<<N_GRAPHS, 256, 0, stream>>>(h2, batch, Wr, br, flag, d_out);
}

// Round 5
// 424.048 us; speedup vs baseline: 1.8486x; 1.8486x over previous
//
#include <hip/hip_runtime.h>
#include <hip/hip_bf16.h>
#include <hip/hip_fp16.h>

#define DEVINL __device__ __forceinline__
typedef __hip_bfloat16 bf16;

typedef __attribute__((ext_vector_type(8))) __bf16 bf16x8;
typedef __attribute__((ext_vector_type(4))) float f32x4;

static constexpr int N_NODES  = 50000;
static constexpr int N_EDGES  = 800000;
static constexpr int N_GRAPHS = 128;
static constexpr float NEG_SLOPE = 0.2f;

// Dual-path input load: isbf=1 -> storage is bf16, else fp32.
DEVINL float ldIn(const void* __restrict__ p, size_t i, int isbf) {
    if (isbf) return __bfloat162float(((const bf16*)p)[i]);
    return ((const float*)p)[i];
}

DEVINL unsigned short f2bf(float f) {
    bf16 b = __float2bfloat16(f);
    return *reinterpret_cast<unsigned short*>(&b);
}

DEVINL unsigned f2hbits(float f) {
    __half h = __float2half(f);
    return (unsigned)*reinterpret_cast<unsigned short*>(&h);
}

DEVINL float hbits2f(unsigned bits) {
    unsigned short us = (unsigned short)bits;
    __half h = *reinterpret_cast<__half*>(&us);
    return __half2float(h);
}

DEVINL float lrelu_exp(float sc) {
    sc = sc > 0.f ? sc : NEG_SLOPE * sc;
    return __expf(sc);
}

// fma two bf16 channels packed in one dword into two f32 accumulators
DEVINL void accw(float w, unsigned wv, float& a0, float& a1) {
    a0 = fmaf(w, __uint_as_float(wv << 16), a0);
    a1 = fmaf(w, __uint_as_float(wv & 0xffff0000u), a1);
}

template<int H>
DEVINL float getse(const uint4& rv, int h) {
    unsigned bits;
    if (H == 4) {
        unsigned w16 = (h & 2) ? rv.z : rv.y;
        bits = (h & 1) ? (w16 >> 16) : (w16 & 0xffffu);
    } else {
        bits = h ? (rv.w >> 16) : (rv.w & 0xffffu);
    }
    return hbits2f(bits);
}

template<int CPL> struct XVT;
template<> struct XVT<16> { using T = uint4; };

// ---------- W[K,M] -> MFMA B-fragment order (device helper) ----------
template<int K, int M>
DEVINL void wfrag_build(const void* __restrict__ W, int isbf,
                        bf16* __restrict__ Wfrag, int idx)
{
    constexpr int KS = K / 32;
    constexpr int total = (M / 16) * KS * 64 * 8;
    if (idx >= total) return;
    int j    = idx & 7;
    int lane = (idx >> 3) & 63;
    int rem  = idx >> 9;
    int ks   = rem % KS;
    int ct   = rem / KS;
    int k = ks * 32 + (lane >> 4) * 8 + j;
    int n = ct * 16 + (lane & 15);
    Wfrag[idx] = __float2bfloat16(ldIn(W, (size_t)k * M + n, isbf));
}

// ---------- fused setup: dtype sniff + cnt zeroing + M matrices + wfrags ----
// Every block sniffs the dtype itself from x (2 KB, L2-hot); block 0 publishes
// the flag. All 257 blocks also zero one element each of cnt (50016 ints) --
// removes the separate hipMemsetAsync dispatch.
// block 0        : M1[d][h] / M2[d][h] = sum_c We[d, h*64+c] * a_e[h, c]
// blocks 1..128  : wfrag for W1 (K=128,M=256)
// blocks 129..256: wfrag for W2 (K=256,M=128)
__global__ __launch_bounds__(256)
void prep_kernel(const unsigned short* __restrict__ xu,
                 const void* __restrict__ We1, const void* __restrict__ ae1,
                 const void* __restrict__ We2, const void* __restrict__ ae2,
                 const void* __restrict__ W1,  const void* __restrict__ W2,
                 int* __restrict__ flagp, int* __restrict__ cnt,
                 float* __restrict__ M1, float* __restrict__ M2,
                 bf16* __restrict__ wf1, bf16* __restrict__ wf2)
{
    __shared__ int sflag;
    const int bx = blockIdx.x;
    const int t  = threadIdx.x;

    // zero cnt (50016 ints over 257*256 threads)
    int zi = bx * 256 + t;
    if (zi < 50016) cnt[zi] = 0;

    if (t < 64) {                       // wave 0, fully active
        int bad = 0;
        for (int i = t; i < 1024; i += 64) {
            unsigned u = xu[2 * i];
            float v = __uint_as_float(u << 16);
            if (!(fabsf(v) <= 1e4f)) bad = 1;
        }
        unsigned long long m = __ballot(bad);
        if (t == 0) sflag = m ? 0 : 1;  // 1 = bf16 storage
    }
    __syncthreads();
    const int isbf = sflag;
    if (bx == 0 && t == 0) *flagp = isbf;

    if (bx == 0) {
        if (t < 64) {
            int d = t >> 2, h = t & 3;
            float s = 0.f;
            for (int c = 0; c < 64; ++c)
                s += ldIn(We1, d * 256 + h * 64 + c, isbf) * ldIn(ae1, h * 64 + c, isbf);
            M1[d * 4 + h] = s;
        }
        if (t < 32) {
            int d = t >> 1, h = t & 1;
            float s = 0.f;
            for (int c = 0; c < 64; ++c)
                s += ldIn(We2, d * 128 + h * 64 + c, isbf) * ldIn(ae2, h * 64 + c, isbf);
            M2[d * 2 + h] = s;
        }
    } else if (bx <= 128) {
        wfrag_build<128, 256>(W1, isbf, wf1, (bx - 1) * 256 + t);
    } else {
        wfrag_build<256, 128>(W2, isbf, wf2, (bx - 129) * 256 + t);
    }
}

// ---------- MFMA GEMM + fused node-score epilogue ----------
template<int K, int M, int AMODE, int H>
__global__ __launch_bounds__(256)
void gemm_mfma_kernel(const void* __restrict__ A, const bf16* __restrict__ Wfrag,
                      bf16* __restrict__ C, const int* __restrict__ flagp, int N,
                      const void* __restrict__ a_src, const void* __restrict__ a_dst,
                      float* __restrict__ sA, float* __restrict__ sD)
{
    constexpr int KS = K / 32, CT = M / 16;
    constexpr int LDA = K + 8;
    __shared__ __align__(16) unsigned short Asm[64 * LDA];
    const int isbf = *flagp;
    const int tid  = threadIdx.x;
    const int wave = tid >> 6, lane = tid & 63;
    const int n0 = blockIdx.x * 64;

    for (int i = tid; i < 64 * (K / 8); i += 256) {
        int r  = i / (K / 8);
        int kc = (i % (K / 8)) * 8;
        int n  = n0 + r;
        unsigned short v[8] = {0, 0, 0, 0, 0, 0, 0, 0};
        if (n < N) {
            size_t base = (size_t)n * K + kc;
            if (AMODE == 1 || isbf) {
                *reinterpret_cast<uint4*>(v) =
                    *reinterpret_cast<const uint4*>((const unsigned short*)A + base);
            } else {
                const float* Af = (const float*)A + base;
                float4 f0 = *reinterpret_cast<const float4*>(Af);
                float4 f1 = *reinterpret_cast<const float4*>(Af + 4);
                v[0] = f2bf(f0.x); v[1] = f2bf(f0.y); v[2] = f2bf(f0.z); v[3] = f2bf(f0.w);
                v[4] = f2bf(f1.x); v[5] = f2bf(f1.y); v[6] = f2bf(f1.z); v[7] = f2bf(f1.w);
            }
        }
        *reinterpret_cast<uint4*>(&Asm[r * LDA + kc]) = *reinterpret_cast<uint4*>(v);
    }
    __syncthreads();

    f32x4 acc[CT];
    #pragma unroll
    for (int ct = 0; ct < CT; ++ct) acc[ct] = (f32x4){0.f, 0.f, 0.f, 0.f};

    const int arow  = wave * 16 + (lane & 15);
    const int akoff = (lane >> 4) * 8;
    #pragma unroll
    for (int ks = 0; ks < KS; ++ks) {
        bf16x8 af = *reinterpret_cast<const bf16x8*>(&Asm[arow * LDA + ks * 32 + akoff]);
        #pragma unroll
        for (int ct = 0; ct < CT; ++ct) {
            bf16x8 bfr = *reinterpret_cast<const bf16x8*>(
                &Wfrag[(((size_t)ct * KS + ks) * 64 + lane) * 8]);
            acc[ct] = __builtin_amdgcn_mfma_f32_16x16x32_bf16(af, bfr, acc[ct], 0, 0, 0);
        }
    }

    const int crow0 = n0 + wave * 16 + (lane >> 4) * 4;
    const int ccol  = lane & 15;
    #pragma unroll
    for (int ct = 0; ct < CT; ++ct) {
        #pragma unroll
        for (int r = 0; r < 4; ++r) {
            int row = crow0 + r;
            if (row < N) C[(size_t)row * M + ct * 16 + ccol] = __float2bfloat16(acc[ct][r]);
        }
    }

    // ---- fused attention logits ----
    float psA[4][H], psD[4][H];
    #pragma unroll
    for (int r = 0; r < 4; ++r)
        #pragma unroll
        for (int hh = 0; hh < H; ++hh) { psA[r][hh] = 0.f; psD[r][hh] = 0.f; }
    #pragma unroll
    for (int ct = 0; ct < CT; ++ct) {
        float as = ldIn(a_src, ct * 16 + ccol, isbf);
        float ad = ldIn(a_dst, ct * 16 + ccol, isbf);
        const int hh = ct >> 2;
        #pragma unroll
        for (int r = 0; r < 4; ++r) {
            psA[r][hh] += acc[ct][r] * as;
            psD[r][hh] += acc[ct][r] * ad;
        }
    }
    #pragma unroll
    for (int m = 1; m < 16; m <<= 1) {
        #pragma unroll
        for (int r = 0; r < 4; ++r)
            #pragma unroll
            for (int hh = 0; hh < H; ++hh) {
                psA[r][hh] += __shfl_xor(psA[r][hh], m);
                psD[r][hh] += __shfl_xor(psD[r][hh], m);
            }
    }
    if (ccol == 0) {
        #pragma unroll
        for (int r = 0; r < 4; ++r) {
            int row = crow0 + r;
            if (row < N) {
                #pragma unroll
                for (int hh = 0; hh < H; ++hh) {
                    sA[(size_t)row * H + hh] = psA[r][hh];
                    sD[(size_t)row * H + hh] = psD[r][hh];
                }
            }
        }
    }
}

// ---------- CSR build: count + per-edge stable rank (atomic return) ----------
__global__ void csr_count_kernel(const int* __restrict__ dst, int* __restrict__ cnt,
                                 int* __restrict__ rank)
{
    int e = blockIdx.x * blockDim.x + threadIdx.x;
    if (e >= N_EDGES) return;
    rank[e] = atomicAdd(&cnt[dst[e]], 1);
}

__global__ __launch_bounds__(256)
void scan_sum_kernel(const int* __restrict__ cnt, int* __restrict__ bsum)
{
    __shared__ int sm[256];
    int i = blockIdx.x * 256 + threadIdx.x;
    sm[threadIdx.x] = (i < N_NODES) ? cnt[i] : 0;
    __syncthreads();
    for (int off = 128; off; off >>= 1) {
        if (threadIdx.x < off) sm[threadIdx.x] += sm[threadIdx.x + off];
        __syncthreads();
    }
    if (threadIdx.x == 0) bsum[blockIdx.x] = sm[0];
}

__global__ __launch_bounds__(256)
void scan_off_kernel(int* __restrict__ bsum, int nb)
{
    __shared__ int sm[256];
    int tid = threadIdx.x;
    int v = (tid < nb) ? bsum[tid] : 0;
    sm[tid] = v;
    __syncthreads();
    for (int off = 1; off < 256; off <<= 1) {
        int t = (tid >= off) ? sm[tid - off] : 0;
        __syncthreads();
        sm[tid] += t;
        __syncthreads();
    }
    if (tid < nb) bsum[tid] = sm[tid] - v;
}

__global__ __launch_bounds__(256)
void scan_final_kernel(const int* __restrict__ cnt, const int* __restrict__ bsum,
                       int* __restrict__ row)
{
    __shared__ int sm[256];
    int i = blockIdx.x * 256 + threadIdx.x;
    int tid = threadIdx.x;
    int v = (i < N_NODES) ? cnt[i] : 0;
    sm[tid] = v;
    __syncthreads();
    for (int off = 1; off < 256; off <<= 1) {
        int t = (tid >= off) ? sm[tid - off] : 0;
        __syncthreads();
        sm[tid] += t;
        __syncthreads();
    }
    int excl = sm[tid] - v + bsum[blockIdx.x];
    if (i < N_NODES) row[i] = excl;
    if (i == N_NODES - 1) row[N_NODES] = excl + v;
}

// ---------- scatter (atomic-free): pos = row[d] + rank[e]; one 16-B record ----------
__global__ void csr_scatter_kernel(const int* __restrict__ srcI, const int* __restrict__ dstI,
                                   const void* __restrict__ eattr, const int* __restrict__ flagp,
                                   const float* __restrict__ M1, const float* __restrict__ M2,
                                   const int* __restrict__ row, const int* __restrict__ rank,
                                   uint4* __restrict__ erec)
{
    const int isbf = *flagp;
    int e = blockIdx.x * blockDim.x + threadIdx.x;
    if (e >= N_EDGES) return;
    float attr[16];
    #pragma unroll
    for (int k = 0; k < 16; ++k) attr[k] = ldIn(eattr, (size_t)e * 16 + k, isbf);
    float4 o1 = {0.f, 0.f, 0.f, 0.f};
    float2 o2 = {0.f, 0.f};
    #pragma unroll
    for (int k = 0; k < 16; ++k) {
        o1.x += attr[k] * M1[k * 4 + 0];
        o1.y += attr[k] * M1[k * 4 + 1];
        o1.z += attr[k] * M1[k * 4 + 2];
        o1.w += attr[k] * M1[k * 4 + 3];
        o2.x += attr[k] * M2[k * 2 + 0];
        o2.y += attr[k] * M2[k * 2 + 1];
    }
    int pos = row[dstI[e]] + rank[e];
    uint4 rec;
    rec.x = (unsigned)srcI[e];
    rec.y = f2hbits(o1.x) | (f2hbits(o1.y) << 16);
    rec.z = f2hbits(o1.z) | (f2hbits(o1.w) << 16);
    rec.w = f2hbits(o2.x) | (f2hbits(o2.y) << 16);
    erec[pos] = rec;
}

// ---------- fused score+softmax+aggregate: one wave per dst, FOUR edges/quad ----
// Round-1 proven-best structure (71 us, 36 VGPR, ~60% occupancy): 16 lanes per
// edge (q = lane>>4), CPL = H*64/16 channels per lane. Full 512-B (L1) / 256-B
// (L2) row reads per edge. Verified at the fabric ceiling for random row
// gathers (~3.45 TB/s at the compulsory 8-XCD-replicated footprint).
// LAYER 1 (H=4): out = relu(agg + b1) -> bf16 h1[N,256]
// LAYER 2 (H=2): out = mean_heads(agg) + b2 -> fp32 h2[N,64]
template<int H, int LAYER>
__global__ __launch_bounds__(256)
void agg_fused_kernel(const int* __restrict__ row, const uint4* __restrict__ erec,
                      const bf16* __restrict__ xs,
                      const float* __restrict__ sA, const float* __restrict__ sD,
                      const void* __restrict__ bias,
                      const int* __restrict__ flagp, void* __restrict__ out)
{
    constexpr int C   = H * 64;         // channels
    constexpr int CPL = C / 16;         // channels per lane (16 / 8)
    constexpr int NQ  = CPL / 8;        // uint4 loads per lane (2 / 1)
    const int isbf = *flagp;
    int dv = (blockIdx.x * 256 + threadIdx.x) >> 6;
    const int d = __builtin_amdgcn_readfirstlane(dv);   // wave-uniform -> scalar loads
    const int lane = threadIdx.x & 63;
    if (d >= N_NODES) return;
    const int q  = lane >> 4;                           // which edge of the quad
    const int sl = lane & 15;                           // slot within the row
    const int h  = (sl * CPL) >> 6;                     // this lane's head
    const char* xsb = (const char*)xs;
    const unsigned lb = (unsigned)(sl * (CPL * 2));     // lane byte offset in a row

    // early loads: self row (address known at entry) + dst-side scores
    uint4 xvS[NQ];
    {
        const uint4* pS = (const uint4*)(xsb + (size_t)((unsigned)d * (C * 2) + lb));
        #pragma unroll
        for (int t = 0; t < NQ; ++t) xvS[t] = pS[t];
    }
    const float sDv = sD[(size_t)d * H + h];
    const float sAd = sA[(size_t)d * H + h];

    float acc[CPL];
    #pragma unroll
    for (int i = 0; i < CPL; ++i) acc[i] = 0.f;
    float den = 0.f, seSum = 0.f;

    const int b = row[d], eend = row[d + 1];
    const int cnt = eend - b;
    const int nb8 = cnt & ~7;

    for (int j0 = b; j0 < b + nb8; j0 += 8) {           // 2 quads = 8 edges / iter
        uint4 rv0 = erec[j0 + q];
        uint4 rv1 = erec[j0 + 4 + q];
        int s0 = (int)rv0.x, s1 = (int)rv1.x;
        const uint4* p0 = (const uint4*)(xsb + (size_t)((unsigned)s0 * (C * 2) + lb));
        const uint4* p1 = (const uint4*)(xsb + (size_t)((unsigned)s1 * (C * 2) + lb));
        uint4 xv0[NQ], xv1[NQ];
        #pragma unroll
        for (int t = 0; t < NQ; ++t) { xv0[t] = p0[t]; xv1[t] = p1[t]; }
        float sa0 = sA[(size_t)s0 * H + h];
        float sa1 = sA[(size_t)s1 * H + h];
        float se0 = getse<H>(rv0, h);
        float se1 = getse<H>(rv1, h);
        float w0 = lrelu_exp(sa0 + sDv + se0);
        float w1 = lrelu_exp(sa1 + sDv + se1);
        seSum += se0 + se1;
        den += w0 + w1;
        const unsigned* wv0 = reinterpret_cast<const unsigned*>(xv0);
        const unsigned* wv1 = reinterpret_cast<const unsigned*>(xv1);
        #pragma unroll
        for (int p = 0; p < CPL / 2; ++p) {
            accw(w0, wv0[p], acc[2 * p], acc[2 * p + 1]);
            accw(w1, wv1[p], acc[2 * p], acc[2 * p + 1]);
        }
    }
    for (int j0 = b + nb8; j0 < eend; j0 += 4) {        // masked tail quads
        int jj = j0 + q;
        bool valid = jj < eend;
        int jc = valid ? jj : (eend - 1);
        uint4 rv = erec[jc];
        int s = (int)rv.x;
        float se = getse<H>(rv, h);
        float sa = sA[(size_t)s * H + h];
        const uint4* p0 = (const uint4*)(xsb + (size_t)((unsigned)s * (C * 2) + lb));
        uint4 xv[NQ];
        #pragma unroll
        for (int t = 0; t < NQ; ++t) xv[t] = p0[t];
        float w = valid ? lrelu_exp(sa + sDv + se) : 0.f;
        seSum += valid ? se : 0.f;
        den += w;
        const unsigned* wv = reinterpret_cast<const unsigned*>(xv);
        #pragma unroll
        for (int p = 0; p < CPL / 2; ++p) accw(w, wv[p], acc[2 * p], acc[2 * p + 1]);
    }

    // cross-quad butterfly reduce (q bits are lane bits 4 and 5)
    #pragma unroll
    for (int i = 0; i < CPL; ++i) {
        acc[i] += __shfl_xor(acc[i], 16);
        acc[i] += __shfl_xor(acc[i], 32);
    }
    den   += __shfl_xor(den, 16);   den   += __shfl_xor(den, 32);
    seSum += __shfl_xor(seSum, 16); seSum += __shfl_xor(seSum, 32);

    // self loop: attr = mean of incident edge attrs -> se_self = seSum/cnt
    {
        const float seM = seSum / fmaxf((float)cnt, 1.f);
        const float wS  = lrelu_exp(sAd + sDv + seM);
        den += wS;
        const unsigned* wv = reinterpret_cast<const unsigned*>(xvS);
        #pragma unroll
        for (int p = 0; p < CPL / 2; ++p) accw(wS, wv[p], acc[2 * p], acc[2 * p + 1]);
    }

    const float rden = 1.f / (den + 1e-16f);
    if (LAYER == 1) {
        if (q == 0) {
            unsigned o[CPL / 2];                         // 8 dwords = 32 B
            #pragma unroll
            for (int p = 0; p < CPL / 2; ++p) {
                float v0 = acc[2 * p] * rden + ldIn(bias, sl * CPL + 2 * p, isbf);
                float v1 = acc[2 * p + 1] * rden + ldIn(bias, sl * CPL + 2 * p + 1, isbf);
                v0 = v0 > 0.f ? v0 : 0.f;
                v1 = v1 > 0.f ? v1 : 0.f;
                o[p] = (unsigned)f2bf(v0) | ((unsigned)f2bf(v1) << 16);
            }
            uint4* op = reinterpret_cast<uint4*>(
                &((unsigned short*)out)[(size_t)d * C + sl * CPL]);
            op[0] = reinterpret_cast<uint4*>(o)[0];
            if (NQ == 2) op[1] = reinterpret_cast<uint4*>(o)[1];
        }
    } else {
        // H=2, CPL=8: lanes sl<8 hold head0 chans sl*8..+7; sl^8 holds head1 same offs
        float v[CPL], pp[CPL];
        #pragma unroll
        for (int i = 0; i < CPL; ++i) {
            v[i] = acc[i] * rden;
            pp[i] = __shfl_xor(v[i], 8);
        }
        if (q == 0 && sl < 8) {
            float o[CPL];
            #pragma unroll
            for (int i = 0; i < CPL; ++i)
                o[i] = 0.5f * (v[i] + pp[i]) + ldIn(bias, sl * CPL + i, isbf);
            float4* op = reinterpret_cast<float4*>(&((float*)out)[(size_t)d * 64 + sl * CPL]);
            op[0] = reinterpret_cast<float4*>(o)[0];
            op[1] = reinterpret_cast<float4*>(o)[1];
        }
    }
}

// ---------- fused pooling + readout (one launch, no gpool buffer) ----------
__global__ __launch_bounds__(256)
void pool_readout_kernel(const float* __restrict__ h2, const int* __restrict__ batch,
                         const void* __restrict__ Wr, const void* __restrict__ br,
                         const int* __restrict__ flagp, void* __restrict__ out)
{
    const int isbf = *flagp;
    int gi = blockIdx.x;
    int lo = 0, hi = N_NODES;
    while (lo < hi) { int mid = (lo + hi) >> 1; if (batch[mid] < gi) lo = mid + 1; else hi = mid; }
    int start = lo;
    lo = start; hi = N_NODES;
    while (lo < hi) { int mid = (lo + hi) >> 1; if (batch[mid] < gi + 1) lo = mid + 1; else hi = mid; }
    int end = lo;
    int c = threadIdx.x & 63, chunk = threadIdx.x >> 6;
    float m = -INFINITY;
    for (int n = start + chunk; n < end; n += 4) m = fmaxf(m, h2[(size_t)n * 64 + c]);
    __shared__ float sm[256];
    sm[threadIdx.x] = m;
    __syncthreads();
    if (threadIdx.x < 64) {
        m = fmaxf(fmaxf(sm[threadIdx.x], sm[threadIdx.x + 64]),
                  fmaxf(sm[threadIdx.x + 128], sm[threadIdx.x + 192]));
        float p = m * ldIn(Wr, threadIdx.x, isbf);
        for (int off = 32; off; off >>= 1) p += __shfl_down(p, off);
        if (threadIdx.x == 0) {
            float r = p + ldIn(br, 0, isbf);
            if (isbf) ((bf16*)out)[gi] = __float2bfloat16(r);
            else      ((float*)out)[gi] = r;
        }
    }
}

extern "C" void kernel_launch(void* const* d_in, const int* in_sizes, int n_in,
                              void* d_out, int out_size, void* d_ws, size_t ws_size,
                              hipStream_t stream)
{
    const void* x     = d_in[0];
    const void* ea    = d_in[1];
    const int*  eidx  = (const int*)d_in[2];
    const int*  batch = (const int*)d_in[3];
    const void* W1  = d_in[4];
    const void* as1 = d_in[5];
    const void* ad1 = d_in[6];
    const void* We1 = d_in[7];
    const void* ae1 = d_in[8];
    const void* b1  = d_in[9];
    const void* W2  = d_in[10];
    const void* as2 = d_in[11];
    const void* ad2 = d_in[12];
    const void* We2 = d_in[13];
    const void* ae2 = d_in[14];
    const void* b2  = d_in[15];
    const void* Wr  = d_in[16];
    const void* br  = d_in[17];

    const int* srcI = eidx;
    const int* dstI = eidx + N_EDGES;

    // ---- workspace layout (float-index offsets), peak ~70 MB ----
    float* ws    = (float*)d_ws;
    bf16*  xs    = (bf16*)ws;                     // [0, 6.4M): N*256 bf16 (L2: N*128)
    bf16*  h1    = (bf16*)(ws + 6400000);         // N*256 bf16 -> [6.4M, 12.8M)
    float* h2    = ws + 6400000;                  // N*64 fp32 overlay (h1 dead after gemm2)
    uint4* erec  = (uint4*)(ws + 12800000);       // E 16-B records -> [12.8M, 16M)
    float* sA1   = ws + 16000000;                 // N*4
    float* sD1   = ws + 16200000;                 // N*4
    float* sA2   = ws + 16400000;                 // N*2
    float* sD2   = ws + 16500000;                 // N*2
    int*   ib    = (int*)(ws + 16600000);
    int*   row    = ib;                           // N+1 (pad 50016)
    int*   cnt    = ib + 50016;                   // N (pad 50016)
    int*   bsum   = ib + 100032;                  // 256 (pad 352)
    int*   rank   = ib + 100384;                  // E
    float* misc  = ws + 16600000 + 900384;
    int*   flag  = (int*)misc;                    // 1
    float* M1    = misc + 16;                     // 64
    float* M2    = misc + 80;                     // 32
    bf16*  wf1   = (bf16*)(misc + 8320);          // 32768 bf16
    bf16*  wf2   = (bf16*)(misc + 8320 + 16384);  // 32768 bf16

    // prep: dtype sniff + cnt zeroing + M1/M2 + both weight fragments
    prep_kernel<<<257, 256, 0, stream>>>((const unsigned short*)x,
                                         We1, ae1, We2, ae2, W1, W2, flag, cnt,
                                         M1, M2, wf1, wf2);

    // ----- CSR over dst (parallel scan) + atomic-free packed-record scatter -----
    const int NB = (N_NODES + 255) / 256;         // 196
    csr_count_kernel<<<(N_EDGES + 255) / 256, 256, 0, stream>>>(dstI, cnt, rank);
    scan_sum_kernel<<<NB, 256, 0, stream>>>(cnt, bsum);
    scan_off_kernel<<<1, 256, 0, stream>>>(bsum, NB);
    scan_final_kernel<<<NB, 256, 0, stream>>>(cnt, bsum, row);
    csr_scatter_kernel<<<(N_EDGES + 255) / 256, 256, 0, stream>>>(
        srcI, dstI, ea, flag, M1, M2, row, rank, erec);

    const int GB = (N_NODES + 63) / 64;           // 782 row-blocks

    // ----- layer 1 (H=4, concat); node scores fused into GEMM epilogue -----
    gemm_mfma_kernel<128, 256, 0, 4><<<GB, 256, 0, stream>>>(
        x, wf1, xs, flag, N_NODES, as1, ad1, sA1, sD1);
    agg_fused_kernel<4, 1><<<(N_NODES + 3) / 4, 256, 0, stream>>>(
        row, erec, xs, sA1, sD1, b1, flag, h1);

    // ----- layer 2 (H=2, mean) -----
    gemm_mfma_kernel<256, 128, 1, 2><<<GB, 256, 0, stream>>>(
        h1, wf2, xs, flag, N_NODES, as2, ad2, sA2, sD2);
    agg_fused_kernel<2, 2><<<(N_NODES + 3) / 4, 256, 0, stream>>>(
        row, erec, xs, sA2, sD2, b2, flag, h2);

    // ----- fused pool + readout -----
    pool_readout_kernel<<<N_GRAPHS, 256, 0, stream>>>(h2, batch, Wr, br, flag, d_out);
}

// Round 6
// 407.242 us; speedup vs baseline: 1.9249x; 1.0413x over previous
//
#include <hip/hip_runtime.h>
#include <hip/hip_bf16.h>
#include <hip/hip_fp16.h>

#define DEVINL __device__ __forceinline__
typedef __hip_bfloat16 bf16;

typedef __attribute__((ext_vector_type(8))) __bf16 bf16x8;
typedef __attribute__((ext_vector_type(4))) float f32x4;

static constexpr int N_NODES  = 50000;
static constexpr int N_EDGES  = 800000;
static constexpr int N_GRAPHS = 128;
static constexpr float NEG_SLOPE = 0.2f;

// Dual-path input load: isbf=1 -> storage is bf16, else fp32.
DEVINL float ldIn(const void* __restrict__ p, size_t i, int isbf) {
    if (isbf) return __bfloat162float(((const bf16*)p)[i]);
    return ((const float*)p)[i];
}

DEVINL unsigned short f2bf(float f) {
    bf16 b = __float2bfloat16(f);
    return *reinterpret_cast<unsigned short*>(&b);
}

DEVINL unsigned f2hbits(float f) {
    __half h = __float2half(f);
    return (unsigned)*reinterpret_cast<unsigned short*>(&h);
}

DEVINL float hbits2f(unsigned bits) {
    unsigned short us = (unsigned short)bits;
    __half h = *reinterpret_cast<__half*>(&us);
    return __half2float(h);
}

DEVINL float lrelu_exp(float sc) {
    sc = sc > 0.f ? sc : NEG_SLOPE * sc;
    return __expf(sc);
}

// fma two bf16 channels packed in one dword into two f32 accumulators
DEVINL void accw(float w, unsigned wv, float& a0, float& a1) {
    a0 = fmaf(w, __uint_as_float(wv << 16), a0);
    a1 = fmaf(w, __uint_as_float(wv & 0xffff0000u), a1);
}

template<int H>
DEVINL float getse(const uint4& rv, int h) {
    unsigned bits;
    if (H == 4) {
        unsigned w16 = (h & 2) ? rv.z : rv.y;
        bits = (h & 1) ? (w16 >> 16) : (w16 & 0xffffu);
    } else {
        bits = h ? (rv.w >> 16) : (rv.w & 0xffffu);
    }
    return hbits2f(bits);
}

// ---------- W[K,M] -> MFMA B-fragment order (device helper) ----------
template<int K, int M>
DEVINL void wfrag_build(const void* __restrict__ W, int isbf,
                        bf16* __restrict__ Wfrag, int idx)
{
    constexpr int KS = K / 32;
    constexpr int total = (M / 16) * KS * 64 * 8;
    if (idx >= total) return;
    int j    = idx & 7;
    int lane = (idx >> 3) & 63;
    int rem  = idx >> 9;
    int ks   = rem % KS;
    int ct   = rem / KS;
    int k = ks * 32 + (lane >> 4) * 8 + j;
    int n = ct * 16 + (lane & 15);
    Wfrag[idx] = __float2bfloat16(ldIn(W, (size_t)k * M + n, isbf));
}

// ---------- fused setup: dtype sniff + cnt zeroing + M matrices + wfrags ----
// Every block sniffs the dtype itself from x (2 KB, L2-hot); block 0 publishes
// the flag. All 257 blocks also zero one element each of cnt (50016 ints) --
// removes the separate hipMemsetAsync dispatch.
// block 0        : M1[d][h] / M2[d][h] = sum_c We[d, h*64+c] * a_e[h, c]
// blocks 1..128  : wfrag for W1 (K=128,M=256)
// blocks 129..256: wfrag for W2 (K=256,M=128)
__global__ __launch_bounds__(256)
void prep_kernel(const unsigned short* __restrict__ xu,
                 const void* __restrict__ We1, const void* __restrict__ ae1,
                 const void* __restrict__ We2, const void* __restrict__ ae2,
                 const void* __restrict__ W1,  const void* __restrict__ W2,
                 int* __restrict__ flagp, int* __restrict__ cnt,
                 float* __restrict__ M1, float* __restrict__ M2,
                 bf16* __restrict__ wf1, bf16* __restrict__ wf2)
{
    __shared__ int sflag;
    const int bx = blockIdx.x;
    const int t  = threadIdx.x;

    // zero cnt (50016 ints over 257*256 threads)
    int zi = bx * 256 + t;
    if (zi < 50016) cnt[zi] = 0;

    if (t < 64) {                       // wave 0, fully active
        int bad = 0;
        for (int i = t; i < 1024; i += 64) {
            unsigned u = xu[2 * i];
            float v = __uint_as_float(u << 16);
            if (!(fabsf(v) <= 1e4f)) bad = 1;
        }
        unsigned long long m = __ballot(bad);
        if (t == 0) sflag = m ? 0 : 1;  // 1 = bf16 storage
    }
    __syncthreads();
    const int isbf = sflag;
    if (bx == 0 && t == 0) *flagp = isbf;

    if (bx == 0) {
        if (t < 64) {
            int d = t >> 2, h = t & 3;
            float s = 0.f;
            for (int c = 0; c < 64; ++c)
                s += ldIn(We1, d * 256 + h * 64 + c, isbf) * ldIn(ae1, h * 64 + c, isbf);
            M1[d * 4 + h] = s;
        }
        if (t < 32) {
            int d = t >> 1, h = t & 1;
            float s = 0.f;
            for (int c = 0; c < 64; ++c)
                s += ldIn(We2, d * 128 + h * 64 + c, isbf) * ldIn(ae2, h * 64 + c, isbf);
            M2[d * 2 + h] = s;
        }
    } else if (bx <= 128) {
        wfrag_build<128, 256>(W1, isbf, wf1, (bx - 1) * 256 + t);
    } else {
        wfrag_build<256, 128>(W2, isbf, wf2, (bx - 129) * 256 + t);
    }
}

// ---------- MFMA GEMM + fused node-score epilogue ----------
template<int K, int M, int AMODE, int H>
__global__ __launch_bounds__(256)
void gemm_mfma_kernel(const void* __restrict__ A, const bf16* __restrict__ Wfrag,
                      bf16* __restrict__ C, const int* __restrict__ flagp, int N,
                      const void* __restrict__ a_src, const void* __restrict__ a_dst,
                      float* __restrict__ sA, float* __restrict__ sD)
{
    constexpr int KS = K / 32, CT = M / 16;
    constexpr int LDA = K + 8;
    __shared__ __align__(16) unsigned short Asm[64 * LDA];
    const int isbf = *flagp;
    const int tid  = threadIdx.x;
    const int wave = tid >> 6, lane = tid & 63;
    const int n0 = blockIdx.x * 64;

    for (int i = tid; i < 64 * (K / 8); i += 256) {
        int r  = i / (K / 8);
        int kc = (i % (K / 8)) * 8;
        int n  = n0 + r;
        unsigned short v[8] = {0, 0, 0, 0, 0, 0, 0, 0};
        if (n < N) {
            size_t base = (size_t)n * K + kc;
            if (AMODE == 1 || isbf) {
                *reinterpret_cast<uint4*>(v) =
                    *reinterpret_cast<const uint4*>((const unsigned short*)A + base);
            } else {
                const float* Af = (const float*)A + base;
                float4 f0 = *reinterpret_cast<const float4*>(Af);
                float4 f1 = *reinterpret_cast<const float4*>(Af + 4);
                v[0] = f2bf(f0.x); v[1] = f2bf(f0.y); v[2] = f2bf(f0.z); v[3] = f2bf(f0.w);
                v[4] = f2bf(f1.x); v[5] = f2bf(f1.y); v[6] = f2bf(f1.z); v[7] = f2bf(f1.w);
            }
        }
        *reinterpret_cast<uint4*>(&Asm[r * LDA + kc]) = *reinterpret_cast<uint4*>(v);
    }
    __syncthreads();

    f32x4 acc[CT];
    #pragma unroll
    for (int ct = 0; ct < CT; ++ct) acc[ct] = (f32x4){0.f, 0.f, 0.f, 0.f};

    const int arow  = wave * 16 + (lane & 15);
    const int akoff = (lane >> 4) * 8;
    #pragma unroll
    for (int ks = 0; ks < KS; ++ks) {
        bf16x8 af = *reinterpret_cast<const bf16x8*>(&Asm[arow * LDA + ks * 32 + akoff]);
        #pragma unroll
        for (int ct = 0; ct < CT; ++ct) {
            bf16x8 bfr = *reinterpret_cast<const bf16x8*>(
                &Wfrag[(((size_t)ct * KS + ks) * 64 + lane) * 8]);
            acc[ct] = __builtin_amdgcn_mfma_f32_16x16x32_bf16(af, bfr, acc[ct], 0, 0, 0);
        }
    }

    const int crow0 = n0 + wave * 16 + (lane >> 4) * 4;
    const int ccol  = lane & 15;
    #pragma unroll
    for (int ct = 0; ct < CT; ++ct) {
        #pragma unroll
        for (int r = 0; r < 4; ++r) {
            int row = crow0 + r;
            if (row < N) C[(size_t)row * M + ct * 16 + ccol] = __float2bfloat16(acc[ct][r]);
        }
    }

    // ---- fused attention logits ----
    float psA[4][H], psD[4][H];
    #pragma unroll
    for (int r = 0; r < 4; ++r)
        #pragma unroll
        for (int hh = 0; hh < H; ++hh) { psA[r][hh] = 0.f; psD[r][hh] = 0.f; }
    #pragma unroll
    for (int ct = 0; ct < CT; ++ct) {
        float as = ldIn(a_src, ct * 16 + ccol, isbf);
        float ad = ldIn(a_dst, ct * 16 + ccol, isbf);
        const int hh = ct >> 2;
        #pragma unroll
        for (int r = 0; r < 4; ++r) {
            psA[r][hh] += acc[ct][r] * as;
            psD[r][hh] += acc[ct][r] * ad;
        }
    }
    #pragma unroll
    for (int m = 1; m < 16; m <<= 1) {
        #pragma unroll
        for (int r = 0; r < 4; ++r)
            #pragma unroll
            for (int hh = 0; hh < H; ++hh) {
                psA[r][hh] += __shfl_xor(psA[r][hh], m);
                psD[r][hh] += __shfl_xor(psD[r][hh], m);
            }
    }
    if (ccol == 0) {
        #pragma unroll
        for (int r = 0; r < 4; ++r) {
            int row = crow0 + r;
            if (row < N) {
                #pragma unroll
                for (int hh = 0; hh < H; ++hh) {
                    sA[(size_t)row * H + hh] = psA[r][hh];
                    sD[(size_t)row * H + hh] = psD[r][hh];
                }
            }
        }
    }
}

// ---------- CSR build: count + per-edge stable rank (atomic return) ----------
__global__ void csr_count_kernel(const int* __restrict__ dst, int* __restrict__ cnt,
                                 int* __restrict__ rank)
{
    int e = blockIdx.x * blockDim.x + threadIdx.x;
    if (e >= N_EDGES) return;
    rank[e] = atomicAdd(&cnt[dst[e]], 1);
}

__global__ __launch_bounds__(256)
void scan_sum_kernel(const int* __restrict__ cnt, int* __restrict__ bsum)
{
    __shared__ int sm[256];
    int i = blockIdx.x * 256 + threadIdx.x;
    sm[threadIdx.x] = (i < N_NODES) ? cnt[i] : 0;
    __syncthreads();
    for (int off = 128; off; off >>= 1) {
        if (threadIdx.x < off) sm[threadIdx.x] += sm[threadIdx.x + off];
        __syncthreads();
    }
    if (threadIdx.x == 0) bsum[blockIdx.x] = sm[0];
}

__global__ __launch_bounds__(256)
void scan_off_kernel(int* __restrict__ bsum, int nb)
{
    __shared__ int sm[256];
    int tid = threadIdx.x;
    int v = (tid < nb) ? bsum[tid] : 0;
    sm[tid] = v;
    __syncthreads();
    for (int off = 1; off < 256; off <<= 1) {
        int t = (tid >= off) ? sm[tid - off] : 0;
        __syncthreads();
        sm[tid] += t;
        __syncthreads();
    }
    if (tid < nb) bsum[tid] = sm[tid] - v;
}

__global__ __launch_bounds__(256)
void scan_final_kernel(const int* __restrict__ cnt, const int* __restrict__ bsum,
                       int* __restrict__ row)
{
    __shared__ int sm[256];
    int i = blockIdx.x * 256 + threadIdx.x;
    int tid = threadIdx.x;
    int v = (i < N_NODES) ? cnt[i] : 0;
    sm[tid] = v;
    __syncthreads();
    for (int off = 1; off < 256; off <<= 1) {
        int t = (tid >= off) ? sm[tid - off] : 0;
        __syncthreads();
        sm[tid] += t;
        __syncthreads();
    }
    int excl = sm[tid] - v + bsum[blockIdx.x];
    if (i < N_NODES) row[i] = excl;
    if (i == N_NODES - 1) row[N_NODES] = excl + v;
}

// ---------- scatter (atomic-free): pos = row[d] + rank[e]; one 16-B record ----------
__global__ void csr_scatter_kernel(const int* __restrict__ srcI, const int* __restrict__ dstI,
                                   const void* __restrict__ eattr, const int* __restrict__ flagp,
                                   const float* __restrict__ M1, const float* __restrict__ M2,
                                   const int* __restrict__ row, const int* __restrict__ rank,
                                   uint4* __restrict__ erec)
{
    const int isbf = *flagp;
    int e = blockIdx.x * blockDim.x + threadIdx.x;
    if (e >= N_EDGES) return;
    float attr[16];
    #pragma unroll
    for (int k = 0; k < 16; ++k) attr[k] = ldIn(eattr, (size_t)e * 16 + k, isbf);
    float4 o1 = {0.f, 0.f, 0.f, 0.f};
    float2 o2 = {0.f, 0.f};
    #pragma unroll
    for (int k = 0; k < 16; ++k) {
        o1.x += attr[k] * M1[k * 4 + 0];
        o1.y += attr[k] * M1[k * 4 + 1];
        o1.z += attr[k] * M1[k * 4 + 2];
        o1.w += attr[k] * M1[k * 4 + 3];
        o2.x += attr[k] * M2[k * 2 + 0];
        o2.y += attr[k] * M2[k * 2 + 1];
    }
    int pos = row[dstI[e]] + rank[e];
    uint4 rec;
    rec.x = (unsigned)srcI[e];
    rec.y = f2hbits(o1.x) | (f2hbits(o1.y) << 16);
    rec.z = f2hbits(o1.z) | (f2hbits(o1.w) << 16);
    rec.w = f2hbits(o2.x) | (f2hbits(o2.y) << 16);
    erec[pos] = rec;
}

// ---------- fused score+softmax+aggregate: one wave per dst, FOUR edges/quad ----
// Round-1 proven-best structure, byte-exact register placement: 16 lanes per
// edge (q = lane>>4), CPL = H*64/16 channels per lane; self-row loaded LATE
// (inside the self-loop block, after the butterflies) -> minimal live range,
// 36 VGPR, ~60% occupancy. Verified at the fabric ceiling for random row
// gathers (~3.45 TB/s at the compulsory 8-XCD-replicated footprint).
// LAYER 1 (H=4): out = relu(agg + b1) -> bf16 h1[N,256]
// LAYER 2 (H=2): out = mean_heads(agg) + b2 -> fp32 h2[N,64]
template<int H, int LAYER>
__global__ __launch_bounds__(256)
void agg_fused_kernel(const int* __restrict__ row, const uint4* __restrict__ erec,
                      const bf16* __restrict__ xs,
                      const float* __restrict__ sA, const float* __restrict__ sD,
                      const void* __restrict__ bias,
                      const int* __restrict__ flagp, void* __restrict__ out)
{
    constexpr int C   = H * 64;         // channels
    constexpr int CPL = C / 16;         // channels per lane (16 / 8)
    constexpr int NQ  = CPL / 8;        // uint4 loads per lane (2 / 1)
    const int isbf = *flagp;
    int dv = (blockIdx.x * 256 + threadIdx.x) >> 6;
    const int d = __builtin_amdgcn_readfirstlane(dv);   // wave-uniform -> scalar loads
    const int lane = threadIdx.x & 63;
    if (d >= N_NODES) return;
    const int q  = lane >> 4;                           // which edge of the quad
    const int sl = lane & 15;                           // slot within the row
    const int h  = (sl * CPL) >> 6;                     // this lane's head
    const char* xsb = (const char*)xs;
    const unsigned lb = (unsigned)(sl * (CPL * 2));     // lane byte offset in a row
    const float sDv = sD[(size_t)d * H + h];
    const float sAd = sA[(size_t)d * H + h];

    float acc[CPL];
    #pragma unroll
    for (int i = 0; i < CPL; ++i) acc[i] = 0.f;
    float den = 0.f, seSum = 0.f;

    const int b = row[d], eend = row[d + 1];
    const int cnt = eend - b;
    const int nb8 = cnt & ~7;

    for (int j0 = b; j0 < b + nb8; j0 += 8) {           // 2 quads = 8 edges / iter
        uint4 rv0 = erec[j0 + q];
        uint4 rv1 = erec[j0 + 4 + q];
        int s0 = (int)rv0.x, s1 = (int)rv1.x;
        const uint4* p0 = (const uint4*)(xsb + (size_t)((unsigned)s0 * (C * 2) + lb));
        const uint4* p1 = (const uint4*)(xsb + (size_t)((unsigned)s1 * (C * 2) + lb));
        uint4 xv0[NQ], xv1[NQ];
        #pragma unroll
        for (int t = 0; t < NQ; ++t) { xv0[t] = p0[t]; xv1[t] = p1[t]; }
        float sa0 = sA[(size_t)s0 * H + h];
        float sa1 = sA[(size_t)s1 * H + h];
        float se0 = getse<H>(rv0, h);
        float se1 = getse<H>(rv1, h);
        float w0 = lrelu_exp(sa0 + sDv + se0);
        float w1 = lrelu_exp(sa1 + sDv + se1);
        seSum += se0 + se1;
        den += w0 + w1;
        const unsigned* wv0 = reinterpret_cast<const unsigned*>(xv0);
        const unsigned* wv1 = reinterpret_cast<const unsigned*>(xv1);
        #pragma unroll
        for (int p = 0; p < CPL / 2; ++p) {
            accw(w0, wv0[p], acc[2 * p], acc[2 * p + 1]);
            accw(w1, wv1[p], acc[2 * p], acc[2 * p + 1]);
        }
    }
    for (int j0 = b + nb8; j0 < eend; j0 += 4) {        // masked tail quads
        int jj = j0 + q;
        bool valid = jj < eend;
        int jc = valid ? jj : (eend - 1);
        uint4 rv = erec[jc];
        int s = (int)rv.x;
        float se = getse<H>(rv, h);
        float sa = sA[(size_t)s * H + h];
        const uint4* p0 = (const uint4*)(xsb + (size_t)((unsigned)s * (C * 2) + lb));
        uint4 xv[NQ];
        #pragma unroll
        for (int t = 0; t < NQ; ++t) xv[t] = p0[t];
        float w = valid ? lrelu_exp(sa + sDv + se) : 0.f;
        seSum += valid ? se : 0.f;
        den += w;
        const unsigned* wv = reinterpret_cast<const unsigned*>(xv);
        #pragma unroll
        for (int p = 0; p < CPL / 2; ++p) accw(w, wv[p], acc[2 * p], acc[2 * p + 1]);
    }

    // cross-quad butterfly reduce (q bits are lane bits 4 and 5)
    #pragma unroll
    for (int i = 0; i < CPL; ++i) {
        acc[i] += __shfl_xor(acc[i], 16);
        acc[i] += __shfl_xor(acc[i], 32);
    }
    den   += __shfl_xor(den, 16);   den   += __shfl_xor(den, 32);
    seSum += __shfl_xor(seSum, 16); seSum += __shfl_xor(seSum, 32);

    // self loop: attr = mean of incident edge attrs -> se_self = seSum/cnt
    // (self-row load happens HERE, late: minimal VGPR live range)
    {
        const float seM = seSum / fmaxf((float)cnt, 1.f);
        const float wS  = lrelu_exp(sAd + sDv + seM);
        const uint4* pS = (const uint4*)(xsb + (size_t)((unsigned)d * (C * 2) + lb));
        uint4 xvS[NQ];
        #pragma unroll
        for (int t = 0; t < NQ; ++t) xvS[t] = pS[t];
        den += wS;
        const unsigned* wv = reinterpret_cast<const unsigned*>(xvS);
        #pragma unroll
        for (int p = 0; p < CPL / 2; ++p) accw(wS, wv[p], acc[2 * p], acc[2 * p + 1]);
    }

    const float rden = 1.f / (den + 1e-16f);
    if (LAYER == 1) {
        if (q == 0) {
            unsigned o[CPL / 2];                         // 8 dwords = 32 B
            #pragma unroll
            for (int p = 0; p < CPL / 2; ++p) {
                float v0 = acc[2 * p] * rden + ldIn(bias, sl * CPL + 2 * p, isbf);
                float v1 = acc[2 * p + 1] * rden + ldIn(bias, sl * CPL + 2 * p + 1, isbf);
                v0 = v0 > 0.f ? v0 : 0.f;
                v1 = v1 > 0.f ? v1 : 0.f;
                o[p] = (unsigned)f2bf(v0) | ((unsigned)f2bf(v1) << 16);
            }
            uint4* op = reinterpret_cast<uint4*>(
                &((unsigned short*)out)[(size_t)d * C + sl * CPL]);
            op[0] = reinterpret_cast<uint4*>(o)[0];
            if (NQ == 2) op[1] = reinterpret_cast<uint4*>(o)[1];
        }
    } else {
        // H=2, CPL=8: lanes sl<8 hold head0 chans sl*8..+7; sl^8 holds head1 same offs
        float v[CPL], pp[CPL];
        #pragma unroll
        for (int i = 0; i < CPL; ++i) {
            v[i] = acc[i] * rden;
            pp[i] = __shfl_xor(v[i], 8);
        }
        if (q == 0 && sl < 8) {
            float o[CPL];
            #pragma unroll
            for (int i = 0; i < CPL; ++i)
                o[i] = 0.5f * (v[i] + pp[i]) + ldIn(bias, sl * CPL + i, isbf);
            float4* op = reinterpret_cast<float4*>(&((float*)out)[(size_t)d * 64 + sl * CPL]);
            op[0] = reinterpret_cast<float4*>(o)[0];
            op[1] = reinterpret_cast<float4*>(o)[1];
        }
    }
}

// ---------- fused pooling + readout (one launch, no gpool buffer) ----------
__global__ __launch_bounds__(256)
void pool_readout_kernel(const float* __restrict__ h2, const int* __restrict__ batch,
                         const void* __restrict__ Wr, const void* __restrict__ br,
                         const int* __restrict__ flagp, void* __restrict__ out)
{
    const int isbf = *flagp;
    int gi = blockIdx.x;
    int lo = 0, hi = N_NODES;
    while (lo < hi) { int mid = (lo + hi) >> 1; if (batch[mid] < gi) lo = mid + 1; else hi = mid; }
    int start = lo;
    lo = start; hi = N_NODES;
    while (lo < hi) { int mid = (lo + hi) >> 1; if (batch[mid] < gi + 1) lo = mid + 1; else hi = mid; }
    int end = lo;
    int c = threadIdx.x & 63, chunk = threadIdx.x >> 6;
    float m = -INFINITY;
    for (int n = start + chunk; n < end; n += 4) m = fmaxf(m, h2[(size_t)n * 64 + c]);
    __shared__ float sm[256];
    sm[threadIdx.x] = m;
    __syncthreads();
    if (threadIdx.x < 64) {
        m = fmaxf(fmaxf(sm[threadIdx.x], sm[threadIdx.x + 64]),
                  fmaxf(sm[threadIdx.x + 128], sm[threadIdx.x + 192]));
        float p = m * ldIn(Wr, threadIdx.x, isbf);
        for (int off = 32; off; off >>= 1) p += __shfl_down(p, off);
        if (threadIdx.x == 0) {
            float r = p + ldIn(br, 0, isbf);
            if (isbf) ((bf16*)out)[gi] = __float2bfloat16(r);
            else      ((float*)out)[gi] = r;
        }
    }
}

extern "C" void kernel_launch(void* const* d_in, const int* in_sizes, int n_in,
                              void* d_out, int out_size, void* d_ws, size_t ws_size,
                              hipStream_t stream)
{
    const void* x     = d_in[0];
    const void* ea    = d_in[1];
    const int*  eidx  = (const int*)d_in[2];
    const int*  batch = (const int*)d_in[3];
    const void* W1  = d_in[4];
    const void* as1 = d_in[5];
    const void* ad1 = d_in[6];
    const void* We1 = d_in[7];
    const void* ae1 = d_in[8];
    const void* b1  = d_in[9];
    const void* W2  = d_in[10];
    const void* as2 = d_in[11];
    const void* ad2 = d_in[12];
    const void* We2 = d_in[13];
    const void* ae2 = d_in[14];
    const void* b2  = d_in[15];
    const void* Wr  = d_in[16];
    const void* br  = d_in[17];

    const int* srcI = eidx;
    const int* dstI = eidx + N_EDGES;

    // ---- workspace layout (float-index offsets), peak ~70 MB ----
    float* ws    = (float*)d_ws;
    bf16*  xs    = (bf16*)ws;                     // [0, 6.4M): N*256 bf16 (L2: N*128)
    bf16*  h1    = (bf16*)(ws + 6400000);         // N*256 bf16 -> [6.4M, 12.8M)
    float* h2    = ws + 6400000;                  // N*64 fp32 overlay (h1 dead after gemm2)
    uint4* erec  = (uint4*)(ws + 12800000);       // E 16-B records -> [12.8M, 16M)
    float* sA1   = ws + 16000000;                 // N*4
    float* sD1   = ws + 16200000;                 // N*4
    float* sA2   = ws + 16400000;                 // N*2
    float* sD2   = ws + 16500000;                 // N*2
    int*   ib    = (int*)(ws + 16600000);
    int*   row    = ib;                           // N+1 (pad 50016)
    int*   cnt    = ib + 50016;                   // N (pad 50016)
    int*   bsum   = ib + 100032;                  // 256 (pad 352)
    int*   rank   = ib + 100384;                  // E
    float* misc  = ws + 16600000 + 900384;
    int*   flag  = (int*)misc;                    // 1
    float* M1    = misc + 16;                     // 64
    float* M2    = misc + 80;                     // 32
    bf16*  wf1   = (bf16*)(misc + 8320);          // 32768 bf16
    bf16*  wf2   = (bf16*)(misc + 8320 + 16384);  // 32768 bf16

    // prep: dtype sniff + cnt zeroing + M1/M2 + both weight fragments
    prep_kernel<<<257, 256, 0, stream>>>((const unsigned short*)x,
                                         We1, ae1, We2, ae2, W1, W2, flag, cnt,
                                         M1, M2, wf1, wf2);

    // ----- CSR over dst (parallel scan) + atomic-free packed-record scatter -----
    const int NB = (N_NODES + 255) / 256;         // 196
    csr_count_kernel<<<(N_EDGES + 255) / 256, 256, 0, stream>>>(dstI, cnt, rank);
    scan_sum_kernel<<<NB, 256, 0, stream>>>(cnt, bsum);
    scan_off_kernel<<<1, 256, 0, stream>>>(bsum, NB);
    scan_final_kernel<<<NB, 256, 0, stream>>>(cnt, bsum, row);
    csr_scatter_kernel<<<(N_EDGES + 255) / 256, 256, 0, stream>>>(
        srcI, dstI, ea, flag, M1, M2, row, rank, erec);

    const int GB = (N_NODES + 63) / 64;           // 782 row-blocks

    // ----- layer 1 (H=4, concat); node scores fused into GEMM epilogue -----
    gemm_mfma_kernel<128, 256, 0, 4><<<GB, 256, 0, stream>>>(
        x, wf1, xs, flag, N_NODES, as1, ad1, sA1, sD1);
    agg_fused_kernel<4, 1><<<(N_NODES + 3) / 4, 256, 0, stream>>>(
        row, erec, xs, sA1, sD1, b1, flag, h1);

    // ----- layer 2 (H=2, mean) -----
    gemm_mfma_kernel<256, 128, 1, 2><<<GB, 256, 0, stream>>>(
        h1, wf2, xs, flag, N_NODES, as2, ad2, sA2, sD2);
    agg_fused_kernel<2, 2><<<(N_NODES + 3) / 4, 256, 0, stream>>>(
        row, erec, xs, sA2, sD2, b2, flag, h2);

    // ----- fused pool + readout -----
    pool_readout_kernel<<<N_GRAPHS, 256, 0, stream>>>(h2, batch, Wr, br, flag, d_out);
}